// Round 7
// baseline (209.562 us; speedup 1.0000x reference)
//
#include <hip/hip_runtime.h>

// NCE loss, fused. N=16384 rows, E=512, V=50257, NR=100 shared noise words.
// loss = mean_rows[ softplus(-x_t) + sum_j softplus(x_nj) ],
//   x = <inp_row, emb_word> + bias_w - log V - logp_noise_w - log NR
//
// R7: MEASUREMENT ROUND. Identical structure to R6, but the main loop runs
// 4x via k-slice rotation (wave w handles slice (w+rep)&3). After 4 reps each
// wave holds the FULL K=512 dot product; the 4-wave LDS combine therefore
// produces 4x the score, rescaled by an exact 0.25f before softplus. Purpose:
// push the kernel above the ~60us harness-fill dispatches so rocprof's top-5
// finally shows its VGPR count, occupancy, VALUBusy and FETCH_SIZE.
// True kernel cost ~= (observed dur)/4.

#define E_SZ   512
#define NROWS  16384
#define NRn    100
#define NWp    112
#define MT     16
#define NBLK   (NROWS / MT)

typedef __attribute__((ext_vector_type(8))) short short8;
typedef __attribute__((ext_vector_type(4))) float f32x4;

#define NTL 15.430077572997398f   // log(V) + log(NR)

__device__ __forceinline__ unsigned int pack2(float a, float b) {
    unsigned int ua = __float_as_uint(a) + 0x8000u;
    unsigned int ub = __float_as_uint(b) + 0x8000u;
    return __builtin_amdgcn_perm(ub, ua, 0x07060302u); // [ua.b2,ua.b3,ub.b2,ub.b3]
}
__device__ __forceinline__ float softplus(float x) {
    return fmaxf(x, 0.f) + log1pf(__expf(-fabsf(x)));
}
__device__ __forceinline__ short8 cvt8(float4 x0, float4 x1) {
    union { unsigned int u[4]; short8 s; } r;
    r.u[0] = pack2(x0.x, x0.y);
    r.u[1] = pack2(x0.z, x0.w);
    r.u[2] = pack2(x1.x, x1.y);
    r.u[3] = pack2(x1.z, x1.w);
    return r.s;
}

// ---- kernel 1: noise rows f32 -> bf16 (nB[kg][word][8], kg=k>>3) + out=0 ----
__global__ __launch_bounds__(128)
void prep_noise(const float* __restrict__ emb, const float* __restrict__ bias,
                const float* __restrict__ lpn, const int* __restrict__ nidx,
                unsigned short* __restrict__ nB,   // (64, 112, 8) bf16
                float* __restrict__ nBn,           // (112,)
                float* __restrict__ out)
{
    const int j = blockIdx.x;          // word slot 0..111
    const int t = threadIdx.x;         // 0..127, elems 4t..4t+3
    const int idx = (j < NRn) ? nidx[j] : 0;
    float4 v = {0.f, 0.f, 0.f, 0.f};
    if (j < NRn) v = *(const float4*)(emb + (size_t)idx * E_SZ + t * 4);
    unsigned int u0 = pack2(v.x, v.y);
    unsigned int u1 = pack2(v.z, v.w);
    const int kg  = t >> 1;            // (4t)>>3
    const int off = (t & 1) * 4;       // (4t)&7
    *(uint2*)(nB + ((size_t)kg * NWp + j) * 8 + off) = make_uint2(u0, u1);
    if (t == 0)
        nBn[j] = (j < NRn) ? (bias[idx] - NTL - lpn[idx]) : 0.f;
    if (j == 0 && t == 0)
        out[0] = 0.f;                  // memset folded in; main kernel ordered after
}

// ---- kernel 2: fused scores + softplus + reduction (x4 rep for profiling) ----
__global__ __launch_bounds__(256, 4)
void nce_loss_kernel(const float* __restrict__ inp,   // (N, E)
                     const float* __restrict__ emb,   // (V, E)
                     const float* __restrict__ bias,  // (V,)
                     const float* __restrict__ lpn,   // (V,)
                     const int*   __restrict__ target,// (N,)
                     const unsigned short* __restrict__ nB,  // (64,112,8) bf16
                     const float* __restrict__ nBn,   // (112,)
                     float* __restrict__ out)
{
    const int t    = threadIdx.x;
    const int w    = t >> 6;
    const int lane = t & 63;
    const int c    = lane & 15;
    const int q    = lane >> 4;
    const int r0   = blockIdx.x * MT;

    __shared__ float sAcc[4 * 2048];   // per-wave disjoint combine slabs, 32 KB
    __shared__ float sBn[NWp];
    __shared__ float sTb[MT];
    __shared__ float sWs[4];

    if (t < NWp) sBn[t] = nBn[t];
    if (t < MT) {
        int tg = target[r0 + t];
        sTb[t] = bias[tg] - NTL - lpn[tg];
    }

    f32x4 accN[7];
    f32x4 accT = {0.f, 0.f, 0.f, 0.f};
#pragma unroll
    for (int ti = 0; ti < 7; ++ti) accN[ti] = {0.f, 0.f, 0.f, 0.f};

    const float* pArow = inp + (size_t)(r0 + c) * E_SZ;
    const float* pTrow = emb + (size_t)target[r0 + c] * E_SZ;

#pragma unroll 1
    for (int rep = 0; rep < 4; ++rep) {
        // k-slice rotation: addresses differ per rep (defeats CSE); the union
        // of 4 reps is the full K=512, so acc ends at 1x full dot product,
        // and the 4-wave combine gives 4x -> rescaled 0.25f in the epilogue.
        const int we = (w + rep) & 3;
        const int kb = we * 128 + q * 8;
        const float* pA = pArow + kb;
        const float* pT = pTrow + kb;
        const unsigned short* pB = nB + ((size_t)(we * 16 + q) * NWp + c) * 8;

        // prologue: B step0; A/T steps 0 and 1 (depth-2 pipeline)
        short8 curB[7];
#pragma unroll
        for (int ti = 0; ti < 7; ++ti) curB[ti] = *(const short8*)(pB + ti * 128);

        float4 a[2][2], tt[2][2];
#pragma unroll
        for (int p = 0; p < 2; ++p) {
            a[p][0]  = *(const float4*)(pA + p * 32);
            a[p][1]  = *(const float4*)(pA + p * 32 + 4);
            tt[p][0] = *(const float4*)(pT + p * 32);
            tt[p][1] = *(const float4*)(pT + p * 32 + 4);
        }

#pragma unroll
        for (int ks = 0; ks < 4; ++ks) {
            const int pb = ks & 1;
            short8 A = cvt8(a[pb][0], a[pb][1]);
            short8 T = cvt8(tt[pb][0], tt[pb][1]);
            short8 Bv[7];
#pragma unroll
            for (int ti = 0; ti < 7; ++ti) Bv[ti] = curB[ti];

            if (ks < 2) {
                a[pb][0]  = *(const float4*)(pA + (ks + 2) * 32);
                a[pb][1]  = *(const float4*)(pA + (ks + 2) * 32 + 4);
                tt[pb][0] = *(const float4*)(pT + (ks + 2) * 32);
                tt[pb][1] = *(const float4*)(pT + (ks + 2) * 32 + 4);
            }
            if (ks < 3) {
                const unsigned short* pBn = pB + (size_t)(ks + 1) * 4 * NWp * 8;
#pragma unroll
                for (int ti = 0; ti < 7; ++ti)
                    curB[ti] = *(const short8*)(pBn + ti * 128);
            }

            accT = __builtin_amdgcn_mfma_f32_16x16x32_bf16(A, T, accT, 0, 0, 0);
#pragma unroll
            for (int ti = 0; ti < 7; ++ti)
                accN[ti] = __builtin_amdgcn_mfma_f32_16x16x32_bf16(A, Bv[ti], accN[ti], 0, 0, 0);
        }
    }

    // ---- combine partials: disjoint slabs, no atomics ----
    float* slab = sAcc + w * 2048;     // slot = tile*256 + reg*64 + lane
#pragma unroll
    for (int ti = 0; ti < 7; ++ti)
#pragma unroll
        for (int r = 0; r < 4; ++r)
            slab[ti * 256 + r * 64 + lane] = accN[ti][r];
#pragma unroll
    for (int r = 0; r < 4; ++r)
        slab[7 * 256 + r * 64 + lane] = accT[r];
    __syncthreads();

    // ---- epilogue: C/D layout col=lane&15, row=(lane>>4)*4+reg ----
    const int ereg = w;
    const int col  = lane & 15;
    const int erow = (lane >> 4) * 4 + ereg;
    float ll = 0.f;
#pragma unroll
    for (int i = 0; i < 7; ++i) {
        int word = i * 16 + col;
        float v = (sAcc[i * 256 + t] + sAcc[2048 + i * 256 + t]
                 + sAcc[4096 + i * 256 + t] + sAcc[6144 + i * 256 + t]) * 0.25f;
        if (word < NRn)
            ll += softplus(v + sBn[word]);
    }
    {
        float v = (sAcc[7 * 256 + t] + sAcc[2048 + 7 * 256 + t]
                 + sAcc[4096 + 7 * 256 + t] + sAcc[6144 + 7 * 256 + t]) * 0.25f;
        if (col == erow)
            ll += softplus(-(v + sTb[erow]));
    }

#pragma unroll
    for (int off = 32; off > 0; off >>= 1) ll += __shfl_down(ll, off);
    if (lane == 0) sWs[w] = ll;
    __syncthreads();
    if (t == 0) {
        float s = (sWs[0] + sWs[1]) + (sWs[2] + sWs[3]);
        atomicAdd(out, s * (1.f / (float)NROWS));
    }
}

extern "C" void kernel_launch(void* const* d_in, const int* in_sizes, int n_in,
                              void* d_out, int out_size, void* d_ws, size_t ws_size,
                              hipStream_t stream) {
    const float* inp    = (const float*)d_in[0];
    const float* emb    = (const float*)d_in[1];
    const float* bias   = (const float*)d_in[2];
    const float* lpn    = (const float*)d_in[3];
    const int*   target = (const int*)d_in[4];
    const int*   nidx   = (const int*)d_in[5];
    float* out = (float*)d_out;

    unsigned short* nB  = (unsigned short*)d_ws;              // 64*112*8*2 = 114688 B
    float*          nBn = (float*)((char*)d_ws + (size_t)64 * NWp * 8 * 2);

    prep_noise<<<NWp, 128, 0, stream>>>(emb, bias, lpn, nidx, nB, nBn, out);
    nce_loss_kernel<<<NBLK, 256, 0, stream>>>(inp, emb, bias, lpn, target, nB, nBn, out);
}